// Round 2
// baseline (3897.611 us; speedup 1.0000x reference)
//
#include <hip/hip_runtime.h>

#define Dd 768
#define Hh 1536
#define Rr 192
#define Ii 1536
#define Ll 12
#define Tt 512
#define Bb 4
#define Mrows 2048
#define Vv 32000

typedef __attribute__((ext_vector_type(4))) float f32x4;
typedef __attribute__((ext_vector_type(8))) short bf16x8;

__device__ __forceinline__ ushort f2bf(float f) {
    union { float f; unsigned u; } x; x.f = f;
    unsigned r = (x.u + 0x7FFFu + ((x.u >> 16) & 1u)) >> 16;
    return (ushort)r;
}

// ---------------- embedding gather ----------------
__global__ __launch_bounds__(256) void embed_kernel(const int* __restrict__ text,
        const float* __restrict__ emb, float* __restrict__ h) {
    int row = blockIdx.x;                // b*512 + s
    int tok = text[row];
    const float* src = emb + (long)tok * Dd;
    float* dst = h + (long)row * Dd;
    for (int d = threadIdx.x; d < Dd; d += 256) dst[d] = src[d];
}

// ---------------- f32 -> bf16 convert ----------------
__global__ __launch_bounds__(256) void cvt_kernel(const float* __restrict__ src,
        ushort* __restrict__ dst, int n4) {
    int i = blockIdx.x * 256 + threadIdx.x;
    int stride = gridDim.x * 256;
    for (; i < n4; i += stride) {
        float4 v = ((const float4*)src)[i];
        ushort4 o = { f2bf(v.x), f2bf(v.y), f2bf(v.z), f2bf(v.w) };
        ((ushort4*)dst)[i] = o;
    }
}

// ---------------- LayerNorm (row of 768) -> bf16 ----------------
__global__ __launch_bounds__(256) void ln_kernel(const float* __restrict__ h,
        const float* __restrict__ g, const float* __restrict__ b,
        ushort* __restrict__ x) {
    int row = blockIdx.x;
    const float* hr = h + (long)row * Dd;
    int tid = threadIdx.x;
    float v0 = hr[tid], v1 = hr[tid + 256], v2 = hr[tid + 512];
    float s = v0 + v1 + v2;
    float ss = v0 * v0 + v1 * v1 + v2 * v2;
    #pragma unroll
    for (int off = 32; off >= 1; off >>= 1) {
        s  += __shfl_down(s, off);
        ss += __shfl_down(ss, off);
    }
    __shared__ float red[8];
    int wave = tid >> 6, lane = tid & 63;
    if (lane == 0) { red[wave] = s; red[wave + 4] = ss; }
    __syncthreads();
    s  = red[0] + red[1] + red[2] + red[3];
    ss = red[4] + red[5] + red[6] + red[7];
    float mean = s * (1.0f / Dd);
    float var = ss * (1.0f / Dd) - mean * mean;
    float rs = rsqrtf(var + 1e-5f);
    ushort* xr = x + (long)row * Dd;
    xr[tid]       = f2bf((v0 - mean) * rs * g[tid]       + b[tid]);
    xr[tid + 256] = f2bf((v1 - mean) * rs * g[tid + 256] + b[tid + 256]);
    xr[tid + 512] = f2bf((v2 - mean) * rs * g[tid + 512] + b[tid + 512]);
}

// ---------------- sequential SSM scan over s ----------------
__global__ __launch_bounds__(256) void scan_kernel(const float* __restrict__ inp,
        const float* __restrict__ gm, const float* __restrict__ bt,
        ushort* __restrict__ states) {
    int idx = blockIdx.x * 256 + threadIdx.x;   // b*H + h   (6144 total)
    int b = idx / Hh, hh = idx - b * Hh;
    float g = gm[hh], be = bt[hh];
    const float* ip = inp + (long)b * Tt * Hh + hh;
    ushort* sp = states + (long)b * Tt * Hh + hh;
    float st = 0.f;
    for (int s = 0; s < Tt; ++s) {
        float y = ip[(long)s * Hh] + st * g + be;
        float e = __expf(2.f * y);
        st = 1.f - 2.f / (e + 1.f);          // tanh(y), inf-safe
        sp[(long)s * Hh] = f2bf(st);
    }
}

// ---------------- bf16 MFMA GEMM: C[M,N] = A[M,K] @ B[K,N] ----------------
// MODE 0: Cf = acc + bias
// MODE 1: Cf += acc + bias     (residual in place)
// MODE 2: Cb = bf16(acc)       (no bias)
// MODE 3: Cb = bf16(ereg_gelu(acc + bias))
template<int MODE>
__global__ __launch_bounds__(256) void gemm_kernel(
        const ushort* __restrict__ A, const ushort* __restrict__ B,
        const float* __restrict__ bias, float* __restrict__ Cf,
        ushort* __restrict__ Cb, int M, int N, int K) {
    __shared__ ushort As[64][32];
    __shared__ ushort Bs[64][32];   // Bs[n][k]
    int tid = threadIdx.x;
    int wave = tid >> 6, lane = tid & 63;
    int wm = wave >> 1, wn = wave & 1;
    int m0 = blockIdx.y * 64, n0 = blockIdx.x * 64;
    int lr = lane & 15, lg = lane >> 4, lk = lg * 8;
    f32x4 acc[2][2] = {};
    int ar = tid >> 2, ac = (tid & 3) * 8;
    int bk = tid >> 3, bn = (tid & 7) * 8;
    const ushort* Aptr = A + (long)(m0 + ar) * K + ac;
    const ushort* Bptr = B + (long)bk * N + n0 + bn;
    for (int k0 = 0; k0 < K; k0 += 32) {
        *(bf16x8*)(&As[ar][ac]) = *(const bf16x8*)(Aptr);
        bf16x8 bv = *(const bf16x8*)(Bptr);
        #pragma unroll
        for (int i = 0; i < 8; ++i) Bs[bn + i][bk] = (ushort)bv[i];
        Aptr += 32;
        Bptr += (long)32 * N;
        __syncthreads();
        bf16x8 a0 = *(const bf16x8*)(&As[wm * 32      + lr][lk]);
        bf16x8 a1 = *(const bf16x8*)(&As[wm * 32 + 16 + lr][lk]);
        bf16x8 b0 = *(const bf16x8*)(&Bs[wn * 32      + lr][lk]);
        bf16x8 b1 = *(const bf16x8*)(&Bs[wn * 32 + 16 + lr][lk]);
        acc[0][0] = __builtin_amdgcn_mfma_f32_16x16x32_bf16(a0, b0, acc[0][0], 0, 0, 0);
        acc[0][1] = __builtin_amdgcn_mfma_f32_16x16x32_bf16(a0, b1, acc[0][1], 0, 0, 0);
        acc[1][0] = __builtin_amdgcn_mfma_f32_16x16x32_bf16(a1, b0, acc[1][0], 0, 0, 0);
        acc[1][1] = __builtin_amdgcn_mfma_f32_16x16x32_bf16(a1, b1, acc[1][1], 0, 0, 0);
        __syncthreads();
    }
    #pragma unroll
    for (int fm = 0; fm < 2; ++fm)
    #pragma unroll
    for (int fn = 0; fn < 2; ++fn) {
        int row = m0 + wm * 32 + fm * 16 + lg * 4;
        int col = n0 + wn * 32 + fn * 16 + lr;
        float bval = (MODE == 0 || MODE == 1 || MODE == 3) ? bias[col] : 0.f;
        #pragma unroll
        for (int r = 0; r < 4; ++r) {
            float v = acc[fm][fn][r] + bval;
            long idx = (long)(row + r) * N + col;
            if (MODE == 0) {
                Cf[idx] = v;
            } else if (MODE == 1) {
                Cf[idx] += v;
            } else if (MODE == 2) {
                Cb[idx] = f2bf(v);
            } else {
                float p = 1.f / (1.f + __expf(-v));
                float ent = -(p * __logf(p + 1e-9f) +
                              (1.f - p) * __logf(1.f - p + 1e-9f));
                float gelu = 0.5f * v * (1.f + erff(v * 0.70710678118654752f));
                Cb[idx] = f2bf(gelu - 0.05f * ent);
            }
        }
    }
}

extern "C" void kernel_launch(void* const* d_in, const int* in_sizes, int n_in,
                              void* d_out, int out_size, void* d_ws, size_t ws_size,
                              hipStream_t stream) {
    const int*   text       = (const int*)  d_in[0];
    const float* text_embed = (const float*)d_in[3];
    const float* ln1_g = (const float*)d_in[8];
    const float* ln1_b = (const float*)d_in[9];
    const float* ln2_g = (const float*)d_in[10];
    const float* ln2_b = (const float*)d_in[11];
    const float* in_w  = (const float*)d_in[12];
    const float* in_b  = (const float*)d_in[13];
    const float* out_w = (const float*)d_in[14];
    const float* out_b = (const float*)d_in[15];
    const float* ssm_g = (const float*)d_in[16];
    const float* ssm_b = (const float*)d_in[17];
    const float* fc1_u = (const float*)d_in[18];
    const float* fc1_v = (const float*)d_in[19];
    const float* fc1_b = (const float*)d_in[20];
    const float* fc2_u = (const float*)d_in[21];
    const float* fc2_v = (const float*)d_in[22];
    const float* fc2_b = (const float*)d_in[23];
    const float* lnf_g = (const float*)d_in[24];
    const float* lnf_b = (const float*)d_in[25];
    const float* head_w = (const float*)d_in[26];
    const float* head_b = (const float*)d_in[27];

    char* wsp = (char*)d_ws;
    size_t used = 0;
    auto alloc = [&](size_t bytes) -> char* {
        char* p = wsp + used;
        used += (bytes + 255) & ~(size_t)255;
        return p;
    };
    const long S_win  = (long)Ll * Dd * Hh;
    const long S_wout = (long)Ll * Hh * Dd;
    const long S_f1u  = (long)Ll * Dd * Rr;
    const long S_f1v  = (long)Ll * Rr * Ii;
    const long S_f2u  = (long)Ll * Ii * Rr;
    const long S_f2v  = (long)Ll * Rr * Dd;
    const long S_head = (long)Dd * Vv;

    ushort* w_in   = (ushort*)alloc(S_win  * 2);
    ushort* w_out  = (ushort*)alloc(S_wout * 2);
    ushort* w_f1u  = (ushort*)alloc(S_f1u  * 2);
    ushort* w_f1v  = (ushort*)alloc(S_f1v  * 2);
    ushort* w_f2u  = (ushort*)alloc(S_f2u  * 2);
    ushort* w_f2v  = (ushort*)alloc(S_f2v  * 2);
    ushort* w_head = (ushort*)alloc(S_head * 2);
    float*  h      = (float*) alloc((long)Mrows * Dd * 4);
    ushort* x      = (ushort*)alloc((long)Mrows * Dd * 2);
    float*  inp    = (float*) alloc((long)Mrows * Hh * 4);   // f32 scan input
    ushort* states = (ushort*)alloc((long)Mrows * Hh * 2);
    ushort* t1     = (ushort*)alloc((long)Mrows * Rr * 2);
    // z aliases inp: inp is dead after scan_kernel in each layer, and z is
    // dead before the next layer's gemm<0> rewrites inp.
    ushort* z      = (ushort*)inp;
    ushort* t2     = t1;   // t1 dead once z is computed

    if (used > ws_size) return;   // fail clean (absmax error) instead of faulting

    auto cvt = [&](const float* s, ushort* d, long n) {
        int n4 = (int)(n / 4);
        int grid = (n4 + 255) / 256; if (grid > 4096) grid = 4096;
        cvt_kernel<<<grid, 256, 0, stream>>>(s, d, n4);
    };
    cvt(in_w,  w_in,  S_win);
    cvt(out_w, w_out, S_wout);
    cvt(fc1_u, w_f1u, S_f1u);
    cvt(fc1_v, w_f1v, S_f1v);
    cvt(fc2_u, w_f2u, S_f2u);
    cvt(fc2_v, w_f2v, S_f2v);
    cvt(head_w, w_head, S_head);

    embed_kernel<<<Mrows, 256, 0, stream>>>(text, text_embed, h);

    for (int l = 0; l < Ll; ++l) {
        ln_kernel<<<Mrows, 256, 0, stream>>>(h, ln1_g + l * Dd, ln1_b + l * Dd, x);
        gemm_kernel<0><<<dim3(Hh / 64, Mrows / 64), 256, 0, stream>>>(
            x, w_in + (long)l * Dd * Hh, in_b + l * Hh, inp, nullptr, Mrows, Hh, Dd);
        scan_kernel<<<(Bb * Hh) / 256, 256, 0, stream>>>(
            inp, ssm_g + l * Hh, ssm_b + l * Hh, states);
        gemm_kernel<1><<<dim3(Dd / 64, Mrows / 64), 256, 0, stream>>>(
            states, w_out + (long)l * Hh * Dd, out_b + l * Dd, h, nullptr, Mrows, Dd, Hh);
        ln_kernel<<<Mrows, 256, 0, stream>>>(h, ln2_g + l * Dd, ln2_b + l * Dd, x);
        gemm_kernel<2><<<dim3(Rr / 64, Mrows / 64), 256, 0, stream>>>(
            x, w_f1u + (long)l * Dd * Rr, nullptr, nullptr, t1, Mrows, Rr, Dd);
        gemm_kernel<3><<<dim3(Ii / 64, Mrows / 64), 256, 0, stream>>>(
            t1, w_f1v + (long)l * Rr * Ii, fc1_b + l * Ii, nullptr, z, Mrows, Ii, Rr);
        gemm_kernel<2><<<dim3(Rr / 64, Mrows / 64), 256, 0, stream>>>(
            z, w_f2u + (long)l * Ii * Rr, nullptr, nullptr, t2, Mrows, Rr, Ii);
        gemm_kernel<1><<<dim3(Dd / 64, Mrows / 64), 256, 0, stream>>>(
            t2, w_f2v + (long)l * Rr * Dd, fc2_b + l * Dd, h, nullptr, Mrows, Dd, Rr);
    }

    ln_kernel<<<Mrows, 256, 0, stream>>>(h, lnf_g, lnf_b, x);
    gemm_kernel<0><<<dim3(Vv / 64, Mrows / 64), 256, 0, stream>>>(
        x, w_head, head_b, (float*)d_out, nullptr, Mrows, Vv, Dd);
}